// Round 3
// baseline (713.196 us; speedup 1.0000x reference)
//
#include <hip/hip_runtime.h>
#include <math.h>

#define NT 365
#define NGRID 30000
#define NX 16
#define HID 256
#define CB 16   // cells per block
#define WVS 4   // waves per block
#define MT 4    // m-tiles (16 hidden rows each) per wave

typedef __attribute__((ext_vector_type(8))) short bf16x8;
typedef __attribute__((ext_vector_type(4))) float f32x4;

static __device__ __forceinline__ short f2bf(float f) {
    union { float f; unsigned u; } v; v.f = f;
    unsigned r = (v.u + 0x7fffu + ((v.u >> 16) & 1u)) >> 16;  // RNE
    return (short)r;
}

// Pre-kernel: w_eff = Wo@Wh (256), b_eff = Wo@bh + bo (scalar).
// ws layout: ws[0..255] = w_eff, ws[256] = b_eff.
__global__ void weff_kernel(const float* __restrict__ Wh, const float* __restrict__ Wo,
                            const float* __restrict__ bh, const float* __restrict__ bo,
                            float* __restrict__ ws) {
    int h = threadIdx.x;  // 256 threads
    float acc = 0.f;
    for (int j = 0; j < HID; ++j)
        acc = fmaf(Wo[j], Wh[j * HID + h], acc);
    ws[h] = acc;

    __shared__ float prod[HID];
    prod[h] = Wo[h] * bh[h];
    __syncthreads();
    if (h == 0) {
        float b = bo[0];
        for (int j = 0; j < HID; ++j) b += prod[j];
        ws[HID] = b;
    }
}

// Block = 16 cells, 4 waves. Wave w computes hidden tiles m = 4w..4w+3
// (4 MFMAs/step), partial dot, cross-wave sum via double-buffered LDS,
// one barrier per timestep. B columns = cells; K: 0..15 x-feats, 16 y_in,
// 17 = 1.0 (bias). A/B packed with the same (hi, j)->k map so any HW
// k-permutation cancels (verified in round 2).
__global__ __launch_bounds__(256, 7) void rnn_mfma4(
    const float* __restrict__ x,   // (NT, NGRID, NX)
    const float* __restrict__ y,   // (NT, NGRID, 1), NaN = missing
    const float* __restrict__ Wi,  // (HID, NX+1)
    const float* __restrict__ bi,  // (HID)
    const float* __restrict__ ws,  // w_eff[256], b_eff
    float* __restrict__ out)       // (NT, NGRID, 1)
{
    __shared__ float red[2][CB][WVS];          // [slot][cell][wave], float4-aligned
    const int tid  = threadIdx.x;
    const int lane = tid & 63;
    const int wv   = tid >> 6;
    const int c    = lane & 15;                // cell / A-row within tile
    const int hi   = lane >> 4;
    const int cell0 = blockIdx.x * CB;

    // ---- A fragments + w_eff for this wave's 4 m-tiles ----
    bf16x8 a[MT];
    float  wef[MT][4];
#pragma unroll
    for (int i = 0; i < MT; ++i) {
        const int m = wv * MT + i;
        const int row = m * 16 + c;
        const float* wrow = Wi + row * (NX + 1);
        bf16x8 av;
        if (hi < 2) {
#pragma unroll
            for (int j = 0; j < 8; ++j) av[j] = f2bf(wrow[hi * 8 + j]);
        } else if (hi == 2) {
            av[0] = f2bf(wrow[16]);            // k=16: weight on y_in
            av[1] = f2bf(bi[row]);             // k=17: bias (x const 1.0)
#pragma unroll
            for (int j = 2; j < 8; ++j) av[j] = 0;
        } else {
#pragma unroll
            for (int j = 0; j < 8; ++j) av[j] = 0;
        }
        a[i] = av;
#pragma unroll
        for (int r = 0; r < 4; ++r)
            wef[i][r] = ws[m * 16 + hi * 4 + r];
    }
    const float b_eff = ws[HID];

    const size_t xoff = (size_t)(cell0 + c) * NX + hi * 8;
    const float* yb = y + cell0 + c;
    float*       ob = out + cell0 + c;

    // x inputs for step 0 (lanes hi<2 hold feats hi*8..hi*8+7 of cell c)
    float4 xa = {0,0,0,0}, xb4 = {0,0,0,0};
    if (hi < 2) {
        const float4* p = (const float4*)(x + xoff);
        xa = p[0]; xb4 = p[1];
    }
    float yo = yb[0];
    float yprev = 0.f;

    for (int t = 0; t < NT; ++t) {
        const float y_in = (yo == yo) ? yo : yprev;    // fillObs

        // ---- B fragment ----
        bf16x8 b;
        if (hi < 2) {
            b[0] = f2bf(xa.x); b[1] = f2bf(xa.y); b[2] = f2bf(xa.z); b[3] = f2bf(xa.w);
            b[4] = f2bf(xb4.x); b[5] = f2bf(xb4.y); b[6] = f2bf(xb4.z); b[7] = f2bf(xb4.w);
        } else if (hi == 2) {
            b[0] = f2bf(y_in);
            b[1] = (short)0x3F80;                      // 1.0 -> bias column
#pragma unroll
            for (int j = 2; j < 8; ++j) b[j] = 0;
        } else {
#pragma unroll
            for (int j = 0; j < 8; ++j) b[j] = 0;
        }

        // prefetch t+1 inputs (regs freed by the pack above; ~full step to land)
        if (t + 1 < NT) {
            if (hi < 2) {
                const float4* p = (const float4*)(x + (size_t)(t + 1) * NGRID * NX + xoff);
                xa = p[0]; xb4 = p[1];
            }
            yo = yb[(size_t)(t + 1) * NGRID];
        }

        // ---- 4 MFMAs + relu + w_eff partial dot ----
        const f32x4 zero4 = {0.f, 0.f, 0.f, 0.f};
        float p0 = 0.f, p1 = 0.f, p2 = 0.f, p3 = 0.f;
#pragma unroll
        for (int i = 0; i < MT; ++i) {
            f32x4 acc = __builtin_amdgcn_mfma_f32_16x16x32_bf16(a[i], b, zero4, 0, 0, 0);
            p0 = fmaf(wef[i][0], fmaxf(acc[0], 0.f), p0);
            p1 = fmaf(wef[i][1], fmaxf(acc[1], 0.f), p1);
            p2 = fmaf(wef[i][2], fmaxf(acc[2], 0.f), p2);
            p3 = fmaf(wef[i][3], fmaxf(acc[3], 0.f), p3);
        }
        float p = (p0 + p1) + (p2 + p3);
        // sum over the 4 hi-groups -> every lane holds its cell's wave-partial
        p += __shfl_xor(p, 16, 64);
        p += __shfl_xor(p, 32, 64);

        // ---- cross-wave combine (double-buffered; one barrier/step) ----
        const int s = t & 1;
        if (lane < 16) red[s][c][wv] = p;
        __syncthreads();
        const float4 v = *(const float4*)&red[s][c][0];
        const float ynew = ((v.x + v.y) + (v.z + v.w)) + b_eff;

        if (wv == 0 && lane < 16) ob[(size_t)t * NGRID] = ynew;
        yprev = ynew;
    }
}

extern "C" void kernel_launch(void* const* d_in, const int* in_sizes, int n_in,
                              void* d_out, int out_size, void* d_ws, size_t ws_size,
                              hipStream_t stream) {
    const float* x  = (const float*)d_in[0];
    const float* y  = (const float*)d_in[1];
    const float* Wi = (const float*)d_in[2];
    const float* bi = (const float*)d_in[3];
    const float* Wh = (const float*)d_in[4];
    const float* bh = (const float*)d_in[5];
    const float* Wo = (const float*)d_in[6];
    const float* bo = (const float*)d_in[7];
    float* out = (float*)d_out;
    float* ws  = (float*)d_ws;

    weff_kernel<<<1, HID, 0, stream>>>(Wh, Wo, bh, bo, ws);
    rnn_mfma4<<<NGRID / CB, 256, 0, stream>>>(x, y, Wi, bi, ws, out);
}

// Round 4
// 414.820 us; speedup vs baseline: 1.7193x; 1.7193x over previous
//
#include <hip/hip_runtime.h>
#include <hip/hip_bf16.h>
#include <math.h>

#define NT 365
#define NGRID 30000
#define NX 16
#define HID 256
#define CB 16   // cells per wave

typedef __attribute__((ext_vector_type(8))) short bf16x8;
typedef __attribute__((ext_vector_type(4))) float f32x4;

static __device__ __forceinline__ short f2bf(float f) {
    return __builtin_bit_cast(short, __float2bfloat16(f));  // RNE, compiler may pack
}

// Pre-kernel: w_eff = Wo@Wh (256), b_eff = Wo@bh + bo (scalar).
// ws layout: ws[0..255] = w_eff, ws[256] = b_eff.
__global__ void weff_kernel(const float* __restrict__ Wh, const float* __restrict__ Wo,
                            const float* __restrict__ bh, const float* __restrict__ bo,
                            float* __restrict__ ws) {
    int h = threadIdx.x;  // 256 threads
    float acc = 0.f;
    for (int j = 0; j < HID; ++j)
        acc = fmaf(Wo[j], Wh[j * HID + h], acc);
    ws[h] = acc;

    __shared__ float prod[HID];
    prod[h] = Wo[h] * bh[h];
    __syncthreads();
    if (h == 0) {
        float b = bo[0];
        for (int j = 0; j < HID; ++j) b += prod[j];
        ws[HID] = b;
    }
}

// One wave = 16 cells, no barriers, no shuffles.
// MFMA-1 (x16): hidden layer, with hidden rows PERMUTED so the C-layout output
//   (col=lane&15, row=4*hi+r; m89-verified) is directly the B-fragment of MFMA-2.
//   Permutation: hidden h(m,i) = 32*(m>>1) + 8*(i>>2) + 4*(m&1) + (i&3).
// MFMA-2 (x8, chained): A2 = w_eff broadcast to all 16 rows -> C2[i,c] = z[c]
//   for every i, i.e. the scalar result lands broadcast in ALL lanes (col=lane&15),
//   with b_eff folded in via C-in. Feedback needs zero cross-lane ops.
// Slot-pairing on A/B fragments cancels any HW k-permutation (both operands use
// the same (hi,j)->k map; verified by rounds 2-3 passing).
__global__ __launch_bounds__(64, 2) void rnn_mfma2(
    const float* __restrict__ x,   // (NT, NGRID, NX)
    const float* __restrict__ y,   // (NT, NGRID, 1), NaN = missing
    const float* __restrict__ Wi,  // (HID, NX+1)
    const float* __restrict__ bi,  // (HID)
    const float* __restrict__ ws,  // w_eff[256], b_eff
    float* __restrict__ out)       // (NT, NGRID, 1)
{
    const int lane = threadIdx.x & 63;
    const int c    = lane & 15;    // A-row / B-col / cell index
    const int hi   = lane >> 4;
    const int cell0 = blockIdx.x * CB;

    // ---- A1 fragments (Wi rows permuted by h(m,i)), resident ----
    bf16x8 a1[16];
#pragma unroll
    for (int m = 0; m < 16; ++m) {
        const int h = 32 * (m >> 1) + 8 * (c >> 2) + 4 * (m & 1) + (c & 3);
        const float* wrow = Wi + h * (NX + 1);
        bf16x8 av;
        if (hi < 2) {
#pragma unroll
            for (int j = 0; j < 8; ++j) av[j] = f2bf(wrow[hi * 8 + j]);
        } else if (hi == 2) {
            av[0] = f2bf(wrow[16]);            // k=16: weight on y_in
            av[1] = f2bf(bi[h]);               // k=17: bias (x const 1.0)
#pragma unroll
            for (int j = 2; j < 8; ++j) av[j] = 0;
        } else {
#pragma unroll
            for (int j = 0; j < 8; ++j) av[j] = 0;
        }
        a1[m] = av;
    }

    // ---- A2 fragments: w_eff in natural hidden order, same value for all rows ----
    bf16x8 a2[8];
#pragma unroll
    for (int ks = 0; ks < 8; ++ks) {
        bf16x8 av;
#pragma unroll
        for (int j = 0; j < 8; ++j) av[j] = f2bf(ws[32 * ks + 8 * hi + j]);
        a2[ks] = av;
    }
    const float b_eff = ws[HID];

    const size_t xoff = (size_t)(cell0 + c) * NX + hi * 8;
    const float* yb = y + cell0 + c;
    float*       ob = out + cell0 + c;

    // ---- depth-2 prefetch pipeline ----
    float4 xa_c = {0,0,0,0}, xb_c = {0,0,0,0};
    float4 xa_n = {0,0,0,0}, xb_n = {0,0,0,0};
    if (hi < 2) {
        const float4* p0 = (const float4*)(x + xoff);
        xa_c = p0[0]; xb_c = p0[1];
        const float4* p1 = (const float4*)(x + (size_t)NGRID * NX + xoff);
        xa_n = p1[0]; xb_n = p1[1];
    }
    float yo_c = yb[0];
    float yo_n = yb[NGRID];
    float yprev = 0.f;

    for (int t = 0; t < NT; ++t) {
        const float y_in = (yo_c == yo_c) ? yo_c : yprev;   // fillObs

        // ---- B1 fragment ----
        bf16x8 b1;
        if (hi < 2) {
            b1[0] = f2bf(xa_c.x); b1[1] = f2bf(xa_c.y);
            b1[2] = f2bf(xa_c.z); b1[3] = f2bf(xa_c.w);
            b1[4] = f2bf(xb_c.x); b1[5] = f2bf(xb_c.y);
            b1[6] = f2bf(xb_c.z); b1[7] = f2bf(xb_c.w);
        } else if (hi == 2) {
            b1[0] = f2bf(y_in);
            b1[1] = (short)0x3F80;                          // 1.0 -> bias column
#pragma unroll
            for (int j = 2; j < 8; ++j) b1[j] = 0;
        } else {
#pragma unroll
            for (int j = 0; j < 8; ++j) b1[j] = 0;
        }

        // issue prefetch for t+2 (lands ~2 steps later)
        float4 xa_f = xa_n, xb_f = xb_n;
        float yo_f = yo_n;
        if (t + 2 < NT) {
            if (hi < 2) {
                const float4* p = (const float4*)(x + (size_t)(t + 2) * NGRID * NX + xoff);
                xa_f = p[0]; xb_f = p[1];
            }
            yo_f = yb[(size_t)(t + 2) * NGRID];
        }

        // ---- hidden layer: 16 independent MFMAs ----
        const f32x4 zero4 = {0.f, 0.f, 0.f, 0.f};
        f32x4 acc1[16];
#pragma unroll
        for (int m = 0; m < 16; ++m)
            acc1[m] = __builtin_amdgcn_mfma_f32_16x16x32_bf16(a1[m], b1, zero4, 0, 0, 0);

        // ---- relu + pack as B2 fragments (slot j<4 from tile 2ks, j>=4 from 2ks+1) ----
        bf16x8 b2[8];
#pragma unroll
        for (int ks = 0; ks < 8; ++ks) {
            bf16x8 v;
#pragma unroll
            for (int r = 0; r < 4; ++r) {
                v[r]     = f2bf(fmaxf(acc1[2 * ks][r],     0.f));
                v[4 + r] = f2bf(fmaxf(acc1[2 * ks + 1][r], 0.f));
            }
            b2[ks] = v;
        }

        // ---- output projection: 8 chained MFMAs, b_eff via C-in ----
        f32x4 acc2 = {b_eff, b_eff, b_eff, b_eff};
#pragma unroll
        for (int ks = 0; ks < 8; ++ks)
            acc2 = __builtin_amdgcn_mfma_f32_16x16x32_bf16(a2[ks], b2[ks], acc2, 0, 0, 0);

        const float ynew = acc2[0];            // z[c]+b_eff, broadcast in every lane

        if (lane < 16) ob[(size_t)t * NGRID] = ynew;
        yprev = ynew;

        // rotate prefetch buffers
        xa_c = xa_n; xb_c = xb_n; yo_c = yo_n;
        xa_n = xa_f; xb_n = xb_f; yo_n = yo_f;
    }
}

extern "C" void kernel_launch(void* const* d_in, const int* in_sizes, int n_in,
                              void* d_out, int out_size, void* d_ws, size_t ws_size,
                              hipStream_t stream) {
    const float* x  = (const float*)d_in[0];
    const float* y  = (const float*)d_in[1];
    const float* Wi = (const float*)d_in[2];
    const float* bi = (const float*)d_in[3];
    const float* Wh = (const float*)d_in[4];
    const float* bh = (const float*)d_in[5];
    const float* Wo = (const float*)d_in[6];
    const float* bo = (const float*)d_in[7];
    float* out = (float*)d_out;
    float* ws  = (float*)d_ws;

    weff_kernel<<<1, HID, 0, stream>>>(Wh, Wo, bh, bo, ws);
    rnn_mfma2<<<NGRID / CB, 64, 0, stream>>>(x, y, Wi, bi, ws, out);
}